// Round 11
// baseline (133.675 us; speedup 1.0000x reference)
//
#include <hip/hip_runtime.h>

#define T_SEQ 2048
#define C_DIM 1024
#define H_DIM 64
#define B_DIM 8
#define NROW (B_DIM * T_SEQ)  // 16384

typedef __attribute__((ext_vector_type(8))) short short8;
typedef __attribute__((ext_vector_type(4))) float f32x4;
typedef __attribute__((ext_vector_type(4))) int i32x4;

__device__ __forceinline__ short f2bf(float f) {
  unsigned u = __builtin_bit_cast(unsigned, f);
  u += 0x7fffu + ((u >> 16) & 1u);  // round-to-nearest-even
  return (short)(u >> 16);
}

// pack two f32 -> one u32 of 2 bf16 (RNE, same bits as f2bf pair)
__device__ __forceinline__ unsigned pk_bf16(float lo, float hi) {
  unsigned r;
  asm("v_cvt_pk_bf16_f32 %0, %1, %2" : "=v"(r) : "v"(lo), "v"(hi));
  return r;
}

// ---------------------------------------------------------------------------
// P: Wt2 in FRAGMENT-LINEAR order (unchanged).
// ---------------------------------------------------------------------------
__global__ __launch_bounds__(256) void w_prep(
    const float* __restrict__ Wq, const float* __restrict__ Wk,
    const float* __restrict__ Wv, short* __restrict__ Wt2) {
  const int unit = blockIdx.x * 256 + threadIdx.x;  // 0..24575
  const int lane = unit & 63;
  const int t = unit >> 6;
  const int kh = t & 3;
  const int g = t >> 2;    // kc*12 + ntg
  const int ntg = g % 12;
  const int kc = g / 12;
  const int n16 = lane & 15, quad = lane >> 4;
  const int mat = ntg >> 2;
  const int h = (ntg & 3) * 16 + n16;
  const int kb = kc * 128 + kh * 32 + quad * 8;
  const float* W = (mat == 0) ? Wq : (mat == 1 ? Wk : Wv);
  short8 v;
#pragma unroll
  for (int e = 0; e < 8; ++e) v[e] = f2bf(W[(size_t)(kb + e) * H_DIM + h]);
  *(short8*)(Wt2 + (size_t)unit * 8) = v;
}

// LDS address (in shorts) for A frag unit (tile, kh, quad, n16); XOR-swizzled.
__device__ __forceinline__ int lds_addr(int tile, int kh, int qd, int nn) {
  return tile * 2048 + kh * 512 + (qd * 16 + (nn ^ ((kh * 4 + qd) & 7))) * 8;
}

// ---------------------------------------------------------------------------
// K1: QKV projection -- exact R10 version (BM=32, grid 512, 3-deep A ring).
// ---------------------------------------------------------------------------
__global__ __launch_bounds__(256, 2) void qkv_gemm(
    const float* __restrict__ x, const short* __restrict__ Wt2,
    short* __restrict__ q, short* __restrict__ k, short* __restrict__ vt) {
  __shared__ __align__(16) short As[2][4096];  // 2 x 8 KB (32 x 128 bf16)
  const int tid = threadIdx.x;
  const int w = tid >> 6, lane = tid & 63;
  const int n16 = lane & 15, quad = lane >> 4;
  const int row0 = blockIdx.x * 32;

  f32x4 acc[2][3];
#pragma unroll
  for (int mt = 0; mt < 2; ++mt)
#pragma unroll
    for (int ln = 0; ln < 3; ++ln) acc[mt][ln] = (f32x4){0.f, 0.f, 0.f, 0.f};

  const int u20 = tid, u21 = 256 + tid;
  const int sr0 = u20 >> 4, f0 = u20 & 15;
  const int sr1 = u21 >> 4, f1 = u21 & 15;
  const float* ap0 = x + (size_t)(row0 + sr0) * C_DIM + f0 * 8;
  const float* ap1 = x + (size_t)(row0 + sr1) * C_DIM + f1 * 8;
  const int soff0 = lds_addr(sr0 >> 4, f0 >> 2, f0 & 3, sr0 & 15);
  const int soff1 = lds_addr(sr1 >> 4, f1 >> 2, f1 & 3, sr1 & 15);

  int swz[4];
#pragma unroll
  for (int kh = 0; kh < 4; ++kh)
    swz[kh] = (quad * 16 + (n16 ^ ((kh * 4 + quad) & 7))) * 8;

  const short* bbase = Wt2 + (size_t)(w * 3) * 2048 + (size_t)lane * 8;

  float4 astg[3][4];  // 3-deep A ring buffer (chunk kc lives in astg[kc%3])
  short8 bfr[12];

#define LOAD_A(d, kcc)                                     \
  {                                                        \
    astg[d][0] = *(const float4*)(ap0 + (kcc) * 128);      \
    astg[d][1] = *(const float4*)(ap0 + (kcc) * 128 + 4);  \
    astg[d][2] = *(const float4*)(ap1 + (kcc) * 128);      \
    astg[d][3] = *(const float4*)(ap1 + (kcc) * 128 + 4);  \
  }

#define STAGE_A(d, p)                                      \
  {                                                        \
    short8 av0, av1;                                       \
    _Pragma("unroll") for (int e = 0; e < 4; ++e) {        \
      av0[e] = f2bf(((const float*)&astg[d][0])[e]);       \
      av0[e + 4] = f2bf(((const float*)&astg[d][1])[e]);   \
      av1[e] = f2bf(((const float*)&astg[d][2])[e]);       \
      av1[e + 4] = f2bf(((const float*)&astg[d][3])[e]);   \
    }                                                      \
    *(short8*)(&As[p][0] + soff0) = av0;                   \
    *(short8*)(&As[p][0] + soff1) = av1;                   \
  }

  // prologue: issue A(0..2) and B(0); stage A(0)
  LOAD_A(0, 0);
  LOAD_A(1, 1);
  LOAD_A(2, 2);
#pragma unroll
  for (int ln = 0; ln < 3; ++ln)
#pragma unroll
    for (int kh = 0; kh < 4; ++kh)
      bfr[ln * 4 + kh] = *(const short8*)(bbase + ln * 2048 + kh * 512);
  STAGE_A(0, 0);  // waits only A(0)'s 4 loads (oldest)
  asm volatile("s_waitcnt lgkmcnt(0)" ::: "memory");
  __builtin_amdgcn_sched_barrier(0);
  __builtin_amdgcn_s_barrier();
  __builtin_amdgcn_sched_barrier(0);

#pragma unroll
  for (int kc = 0; kc < 8; ++kc) {
    const short* asb = &As[kc & 1][0];
#pragma unroll
    for (int kh = 0; kh < 4; ++kh) {
      const short8 a0 = *(const short8*)(asb + kh * 512 + swz[kh]);
      const short8 a1 = *(const short8*)(asb + 2048 + kh * 512 + swz[kh]);
#pragma unroll
      for (int ln = 0; ln < 3; ++ln) {
        acc[0][ln] = __builtin_amdgcn_mfma_f32_16x16x32_bf16(
            a0, bfr[ln * 4 + kh], acc[0][ln], 0, 0, 0);
        acc[1][ln] = __builtin_amdgcn_mfma_f32_16x16x32_bf16(
            a1, bfr[ln * 4 + kh], acc[1][ln], 0, 0, 0);
      }
    }
    if (kc < 7) {
      const short* bc = bbase + (size_t)(kc + 1) * 24576;
#pragma unroll
      for (int ln = 0; ln < 3; ++ln)
#pragma unroll
        for (int kh = 0; kh < 4; ++kh)
          bfr[ln * 4 + kh] = *(const short8*)(bc + ln * 2048 + kh * 512);
      if (kc < 5) {
        LOAD_A(kc % 3, kc + 3);
      }
      STAGE_A((kc + 1) % 3, (kc + 1) & 1);
      asm volatile("s_waitcnt lgkmcnt(0)" ::: "memory");
      __builtin_amdgcn_sched_barrier(0);
      __builtin_amdgcn_s_barrier();
      __builtin_amdgcn_sched_barrier(0);
    }
  }
#undef STAGE_A
#undef LOAD_A

  const int b = row0 >> 11;
#pragma unroll
  for (int mt = 0; mt < 2; ++mt)
#pragma unroll
    for (int ln = 0; ln < 3; ++ln) {
      const int ntg = w * 3 + ln;
      const int mat = ntg >> 2;
      const int cl = (ntg & 3) * 16 + n16;
#pragma unroll
      for (int r = 0; r < 4; ++r) {
        const int row = row0 + mt * 16 + quad * 4 + r;
        const float v = acc[mt][ln][r];
        if (mat == 0)
          q[(size_t)row * H_DIM + cl] = f2bf(v * 0.125f);
        else if (mat == 1)
          k[(size_t)row * H_DIM + cl] = f2bf(v);
        else
          vt[((size_t)b * H_DIM + cl) * T_SEQ + (row & (T_SEQ - 1))] = f2bf(v);
      }
    }
}

// ---------------------------------------------------------------------------
// K2: QUARTET-tile flash attention + in-register softmax + IN-PLACE K/V
// PREFETCH.  The quartet kernel runs at 1 wave/SIMD (grid 256 = 1 block/CU,
// 4 waves) -- ZERO TLP, so every load's latency is fully exposed (model:
// ~12us of the ~29us is stall).  Fix with no register cost: bk is dead after
// the QK/exp t-loop, so jt+4's K loads overwrite it IN PLACE right there
// (latency hides under V-issue + 4 tiles of EXCHANGE+PV, ~500-600cy); bv is
// dead after the PV t-loop, so jt+4's V loads overwrite it there (consumed
// ~1700cy later).  vs R5's failed version: no double-buffer arrays (+0 VGPR
// vs +64) and a compute-rich iteration to hide under.  Same values, same
// MFMA order -> absmax bit-identical.
// ---------------------------------------------------------------------------
__global__ __launch_bounds__(256) void attn_mfma(
    const short* __restrict__ q, const short* __restrict__ k,
    const short* __restrict__ vt, float* __restrict__ out) {
  __shared__ __align__(16) float oshare[3][4096];  // 4 tiles x 1024
  __shared__ __align__(16) float lshare[3][1024];  // 4 tiles x 256
  const int tid = threadIdx.x;
  const int w = tid >> 6;
  const int lane = tid & 63;
  const int n16 = lane & 15, quad = lane >> 4;
  const int b = blockIdx.x & 7;   // b == XCD slot -> K/V L2-resident
  const int g = blockIdx.x >> 3;  // 0..31

  int r0t[4], nj[4];
  r0t[0] = g * 16;
  r0t[1] = (63 - g) * 16;
  r0t[2] = (64 + g) * 16;
  r0t[3] = (127 - g) * 16;
#pragma unroll
  for (int t = 0; t < 4; ++t) nj[t] = (r0t[t] + 79) >> 6;

  const short* kb = k + (size_t)b * T_SEQ * H_DIM;
  const short* vb = vt + (size_t)b * H_DIM * T_SEQ;

  short8 aq[4][2];
#pragma unroll
  for (int t = 0; t < 4; ++t) {
    const short* qp = q + ((size_t)b * T_SEQ + r0t[t] + n16) * H_DIM;
    aq[t][0] = *(const short8*)(qp + quad * 8);
    aq[t][1] = *(const short8*)(qp + 32 + quad * 8);
  }

  f32x4 O[4][4];
#pragma unroll
  for (int t = 0; t < 4; ++t)
#pragma unroll
    for (int i = 0; i < 4; ++i) O[t][i] = (f32x4){0.f, 0.f, 0.f, 0.f};
  float lssc[4] = {0.f, 0.f, 0.f, 0.f};  // per-lane partial for row = n16

  short8 bk[4][2], bv[4][2];

#define LOADK(J0)                                                             \
  _Pragma("unroll") for (int nt = 0; nt < 4; ++nt) {                          \
    const short* kp = kb + (size_t)((J0) + nt * 16 + n16) * H_DIM + quad * 8; \
    bk[nt][0] = *(const short8*)kp;                                           \
    bk[nt][1] = *(const short8*)(kp + 32);                                    \
  }
#define LOADV(J0)                                                             \
  _Pragma("unroll") for (int ht = 0; ht < 4; ++ht)                            \
  _Pragma("unroll") for (int kh = 0; kh < 2; ++kh)                            \
      bv[ht][kh] = *(const short8*)(vb + (size_t)(ht * 16 + n16) * T_SEQ +    \
                                    (J0) + kh * 32 + quad * 8);

  // prologue: first j-tile's K and V in flight
  LOADK(w * 64);
  LOADV(w * 64);

  for (int jt = w; jt < nj[3]; jt += 4) {
    const int j0 = jt * 64;
    const int jn = jt + 4;

    // --- per tile: swapped QK, exp+mask, register pack (consumes bk) ---
    unsigned wp[4][4][2];
#pragma unroll
    for (int t = 0; t < 4; ++t) {
      if (jt < nj[t]) {  // wave-uniform
        f32x4 s[4];
#pragma unroll
        for (int nt = 0; nt < 4; ++nt) {
          f32x4 z = (f32x4){0.f, 0.f, 0.f, 0.f};
          z = __builtin_amdgcn_mfma_f32_16x16x32_bf16(bk[nt][0], aq[t][0], z, 0, 0, 0);
          z = __builtin_amdgcn_mfma_f32_16x16x32_bf16(bk[nt][1], aq[t][1], z, 0, 0, 0);
          s[nt] = z;
        }
        const bool full = (j0 + 64 <= r0t[t]);
#pragma unroll
        for (int nt = 0; nt < 4; ++nt) {
          float p[4];
#pragma unroll
          for (int r = 0; r < 4; ++r) {
            if (full) {
              p[r] = __expf(s[nt][r]);
            } else {
              const int j = j0 + nt * 16 + quad * 4 + r;
              p[r] = (j <= r0t[t] + n16) ? __expf(s[nt][r]) : 0.f;
            }
            lssc[t] += p[r];
          }
          wp[t][nt][0] = pk_bf16(p[0], p[1]);
          wp[t][nt][1] = pk_bf16(p[2], p[3]);
        }
      }
    }

    // bk is dead: prefetch next iter's K IN PLACE (latency hides under
    // EXCHANGE+PV of 4 tiles below)
    if (jn < nj[3]) {
      LOADK(jn * 64);
    }

    // --- in-register exchange -> PV A-fragments, then PV (consumes bv) ---
#define EXCHANGE(WSRC, AP0, AP1)                                          \
  {                                                                       \
    i32x4 apw[2];                                                         \
    _Pragma("unroll") for (int h = 0; h < 2; ++h) {                       \
      _Pragma("unroll") for (int ww = 0; ww < 2; ++ww) {                  \
        const unsigned wlo = WSRC[2 * h][ww];                             \
        const unsigned whi = WSRC[2 * h + 1][ww];                         \
        const unsigned pay16 = (quad >= 2) ? whi : wlo;                   \
        const unsigned pay2 = (quad < 2) ? whi : wlo;                     \
        const unsigned x16 = (unsigned)__shfl_xor((int)pay16, 16);        \
        const unsigned x32 = (unsigned)__shfl_xor((int)pay2, 32);         \
        const unsigned x48 = (unsigned)__shfl_xor((int)pay2, 48);         \
        const unsigned lo =                                               \
            quad == 0 ? wlo : quad == 1 ? x48 : quad == 2 ? x32 : x16;    \
        const unsigned hi =                                               \
            quad == 0 ? x16 : quad == 1 ? x32 : quad == 2 ? x48 : whi;    \
        apw[h][ww] = (int)lo;                                             \
        apw[h][2 + ww] = (int)hi;                                         \
      }                                                                   \
    }                                                                     \
    AP0 = __builtin_bit_cast(short8, apw[0]);                             \
    AP1 = __builtin_bit_cast(short8, apw[1]);                             \
  }

#pragma unroll
    for (int t = 0; t < 4; ++t) {
      if (jt < nj[t]) {  // wave-uniform
        short8 ap0, ap1;
        EXCHANGE(wp[t], ap0, ap1);
#pragma unroll
        for (int ht = 0; ht < 4; ++ht) {
          O[t][ht] = __builtin_amdgcn_mfma_f32_16x16x32_bf16(ap0, bv[ht][0], O[t][ht], 0, 0, 0);
          O[t][ht] = __builtin_amdgcn_mfma_f32_16x16x32_bf16(ap1, bv[ht][1], O[t][ht], 0, 0, 0);
        }
      }
    }
#undef EXCHANGE

    // bv is dead: prefetch next iter's V IN PLACE (consumed after next
    // iter's QK+exp section, ~1700cy of cover)
    if (jn < nj[3]) {
      LOADV(jn * 64);
    }
  }
#undef LOADK
#undef LOADV

  // remap scalar row-partials (row = n16) to the (quad,r) convention:
  // row (quad*4+r)'s four quad-partials land at n16 = 0..3; zeros elsewhere.
  // The unchanged epilogue's xor(1,2,4,8) reduction then sums them exactly.
  float ls[4][4];
#pragma unroll
  for (int t = 0; t < 4; ++t)
#pragma unroll
    for (int r = 0; r < 4; ++r) {
      const int src = (n16 & 3) * 16 + quad * 4 + r;
      const float v = __shfl(lssc[t], src);
      ls[t][r] = (n16 < 4) ? v : 0.f;
    }

  // --- cross-wave reduction (R2 pattern, 4 tiles) ---
  if (w != 0) {
#pragma unroll
    for (int t = 0; t < 4; ++t) {
#pragma unroll
      for (int ht = 0; ht < 4; ++ht)
#pragma unroll
        for (int r = 0; r < 4; ++r)
          oshare[w - 1][t * 1024 + (ht * 4 + r) * 64 + lane] = O[t][ht][r];
#pragma unroll
      for (int r = 0; r < 4; ++r)
        lshare[w - 1][t * 256 + r * 64 + lane] = ls[t][r];
    }
  }
  __syncthreads();
  if (w == 0) {
#pragma unroll
    for (int t = 0; t < 4; ++t) {
#pragma unroll
      for (int ht = 0; ht < 4; ++ht)
#pragma unroll
        for (int r = 0; r < 4; ++r) {
          float a = O[t][ht][r];
#pragma unroll
          for (int ow = 0; ow < 3; ++ow)
            a += oshare[ow][t * 1024 + (ht * 4 + r) * 64 + lane];
          O[t][ht][r] = a;
        }
#pragma unroll
      for (int r = 0; r < 4; ++r) {
        float va = ls[t][r];
#pragma unroll
        for (int ow = 0; ow < 3; ++ow)
          va += lshare[ow][t * 256 + r * 64 + lane];
        va += __shfl_xor(va, 1);
        va += __shfl_xor(va, 2);
        va += __shfl_xor(va, 4);
        va += __shfl_xor(va, 8);
        ls[t][r] = va;
      }
#pragma unroll
      for (int ht = 0; ht < 4; ++ht)
#pragma unroll
        for (int r = 0; r < 4; ++r)
          out[((size_t)b * T_SEQ + r0t[t] + quad * 4 + r) * H_DIM + ht * 16 +
              n16] = O[t][ht][r] / ls[t][r];
    }
  }
}

extern "C" void kernel_launch(void* const* d_in, const int* in_sizes, int n_in,
                              void* d_out, int out_size, void* d_ws,
                              size_t ws_size, hipStream_t stream) {
  const float* x = (const float*)d_in[0];
  const float* Wq = (const float*)d_in[1];
  const float* Wk = (const float*)d_in[2];
  const float* Wv = (const float*)d_in[3];

  char* ws = (char*)d_ws;
  short* Wt = (short*)ws;                       // 384 KB (fragment-linear)
  short* q = (short*)(ws + 3 * 64 * 1024 * 2);  // 2 MB each
  short* kk = (short*)(ws + 3 * 64 * 1024 * 2 + 2097152);
  short* vt = (short*)(ws + 3 * 64 * 1024 * 2 + 2 * 2097152);

  w_prep<<<96, 256, 0, stream>>>(Wq, Wk, Wv, Wt);
  qkv_gemm<<<NROW / 32, 256, 0, stream>>>(x, Wt, q, kk, vt);
  attn_mfma<<<B_DIM * (T_SEQ / 64), 256, 0, stream>>>(q, kk, vt, (float*)d_out);
}